// Round 6
// baseline (1419.165 us; speedup 1.0000x reference)
//
#include <hip/hip_runtime.h>

#define TB 512   // batch
#define TT 1024  // time
#define TD 64    // input dim
#define TH 128   // hidden
#define NRB 4    // batch rows per block = 2 tiles x 2 rows -> 128 blocks

typedef __attribute__((ext_vector_type(8))) short short8;  // 8 bf16 (4 VGPRs)
typedef __attribute__((ext_vector_type(4))) float f32x4;   // MFMA C/D

#define LOG2E 1.44269504f

// fp32 -> bf16 bits, round-to-nearest-even
__device__ __forceinline__ short bfb(float f) {
    unsigned u = __builtin_bit_cast(unsigned, f);
    u = (u + 0x7FFFu + ((u >> 16) & 1u)) >> 16;
    return (short)u;
}

// Barrier with LDS-only drain: global loads/stores stay in flight across it.
#define BAR() asm volatile("s_waitcnt lgkmcnt(0)\n\ts_barrier" ::: "memory")
// compiler-only ordering fence for intra-wave DS write->read
#define WAVE_FENCE() asm volatile("" ::: "memory")

// ---------------- phase 1: x -> bf16 A-fragment order ----------------------
// ws layout (short8 units): [blk 0..127][t][kt 0..1][e 0..15], e = c*4 + quad
// holds x[blk*4 + c][t][32*kt + 8*quad + j], j=0..7   (c = global row 0..3)
__global__ __launch_bounds__(256)
void xswz(const float* __restrict__ x, short8* __restrict__ ws) {
    int gid = blockIdx.x * 256 + threadIdx.x;   // 128*1024*2*16 = 4.19M
    int e   = gid & 15;
    int kt  = (gid >> 4) & 1;
    int t   = (gid >> 5) & (TT - 1);
    int blk = gid >> 15;
    int c = e >> 2, quad = e & 3;
    const float* p = x + ((size_t)(blk * NRB + c) * TT + t) * TD + 32 * kt + 8 * quad;
    f32x4 a = *(const f32x4*)p;
    f32x4 b = *(const f32x4*)(p + 4);
    short8 f;
    #pragma unroll
    for (int j = 0; j < 4; ++j) { f[j] = bfb(a[j]); f[4 + j] = bfb(b[j]); }
    ws[gid] = f;
}

// ---------------- phase 2: the scan -----------------------------------------
// 128 blocks x 512 threads. Block owns 4 batch rows as TWO INDEPENDENT TILES
// (tile0 = rows Bb+0..1, tile1 = rows Bb+2..3). The two tiles' chains overlap
// (ILP-2) through every latency segment; weights (B-frags) are shared.
// Wave w owns gate cols {16w+c, +128, +256}. quad0 lanes hold the real C/D
// rows; intra-wave LDS exchange hands lane (quad,c) the triple for
// (tile=quad>>1, row=quad&1, col=16w+c).
template <bool USE_WS>
__global__ __launch_bounds__(512, 2)
void gru_mfma(const float* __restrict__ x, const short8* __restrict__ xw,
              const float* __restrict__ mask,
              const float* __restrict__ w_ih, const float* __restrict__ w_hh,
              const float* __restrict__ b_ih, const float* __restrict__ b_hh,
              const float* __restrict__ Wo, const float* __restrict__ bo,
              float* __restrict__ out)
{
    __shared__ short hbuf[2][2][2][136];    // [tile][buf][row<2][k+pad] 2.2KB
    __shared__ float exws[8][2][4][16][4];  // [wave][tile][acc][c][row] 16KB
    __shared__ float mlds[TT][4];           // mask slice (16KB)

    const int tid  = threadIdx.x;
    const int w    = tid >> 6;
    const int lane = tid & 63;
    const int c    = lane & 15;
    const int quad = lane >> 4;
    const int Bb   = blockIdx.x * NRB;

    // ---- one-time staging ----
    for (int i = tid; i < TT * 4; i += 512) {
        int t = i >> 2, b = i & 3;
        mlds[t][b] = mask[(size_t)(Bb + b) * TT + t];
    }
    for (int i = tid; i < 2 * 2 * 2 * 136; i += 512) (&hbuf[0][0][0][0])[i] = 0;

    const int jj = 16 * w + c;            // gate column this lane owns

    // ---- weights -> bf16 B-fragments in registers (shared by both tiles) ----
    short8 whh[3][4], wih[3][2], wof[4];
    {
        const int gg[3] = {jj, TH + jj, 2 * TH + jj};
        #pragma unroll
        for (int g = 0; g < 3; ++g) {
            #pragma unroll
            for (int kt = 0; kt < 4; ++kt) {
                const float* p = w_hh + (size_t)gg[g] * TH + 32 * kt + 8 * quad;
                short8 f;
                #pragma unroll
                for (int j = 0; j < 8; ++j) f[j] = bfb(p[j]);
                whh[g][kt] = f;
            }
            #pragma unroll
            for (int kt = 0; kt < 2; ++kt) {
                const float* p = w_ih + (size_t)gg[g] * TD + 32 * kt + 8 * quad;
                short8 f;
                #pragma unroll
                for (int j = 0; j < 8; ++j) f[j] = bfb(p[j]);
                wih[g][kt] = f;
            }
        }
        #pragma unroll
        for (int kt = 0; kt < 4; ++kt) {
            short8 f = {0,0,0,0,0,0,0,0};
            if (c < 2) {
                const float* p = Wo + (size_t)c * TH + 32 * kt + 8 * quad;
                #pragma unroll
                for (int j = 0; j < 8; ++j) f[j] = bfb(p[j]);
            }
            wof[kt] = f;
        }
    }

    // epilogue constants for col jj
    const float crK = -LOG2E * (b_ih[jj] + b_hh[jj]);
    const float czK = -LOG2E * (b_ih[TH + jj] + b_hh[TH + jj]);
    const float bin = b_ih[2 * TH + jj];
    const float bhn = b_hh[2 * TH + jj];
    const float boc = (c < 2) ? bo[c] : 0.0f;

    const short8 z8 = {0,0,0,0,0,0,0,0};
    const f32x4  z4 = {0.f,0.f,0.f,0.f};

    // x bases (tile0: global rows c 0..1 -> e = c*4+quad; tile1: e = (c+2)*4+quad)
    const short8* xwpA = xw + (size_t)blockIdx.x * (TT * 32) + (c * 4 + quad);
    const short8* xwpB = xwpA + 8;
    const float*  xrowA = x + (size_t)(Bb + (c & 1)) * TT * TD + 8 * quad;
    const float*  xrowB = x + (size_t)(Bb + 2 + (c & 1)) * TT * TD + 8 * quad;

    short8 xfA0[2] = {z8, z8}, xfA1[2] = {z8, z8};
    short8 xfB0[2] = {z8, z8}, xfB1[2] = {z8, z8};
    if (c < 2) {
        if (USE_WS) {
            xfA0[0] = xwpA[0];  xfA0[1] = xwpA[16];
            xfB0[0] = xwpB[0];  xfB0[1] = xwpB[16];
        } else {
            #pragma unroll
            for (int kt = 0; kt < 2; ++kt) {
                f32x4 a = *(const f32x4*)(xrowA + 32 * kt);
                f32x4 b = *(const f32x4*)(xrowA + 32 * kt + 4);
                f32x4 a2 = *(const f32x4*)(xrowB + 32 * kt);
                f32x4 b2 = *(const f32x4*)(xrowB + 32 * kt + 4);
                short8 f = z8, f2 = z8;
                #pragma unroll
                for (int j = 0; j < 4; ++j) {
                    f[j] = bfb(a[j]);   f[4 + j] = bfb(b[j]);
                    f2[j] = bfb(a2[j]); f2[4 + j] = bfb(b2[j]);
                }
                xfA0[kt] = f; xfB0[kt] = f2;
            }
        }
    }

    float hold = 0.0f;    // h for (tile=quad>>1, row=quad&1, col=jj)
    const int tl = quad >> 1, rw = quad & 1;

#define STEP(T, XA, XAN, XB, XBN)                                               \
  {                                                                             \
    const int t = (T);                                                          \
    BAR();                                                                      \
    const int rb = t & 1, wb = rb ^ 1;                                          \
    short8 haA[4], haB[4];                                                      \
    _Pragma("unroll")                                                           \
    for (int kt = 0; kt < 4; ++kt) { haA[kt] = z8; haB[kt] = z8; }              \
    if (c < 2) {    /* only real A-rows; D rows 2..15 are never read */         \
        _Pragma("unroll")                                                       \
        for (int kt = 0; kt < 4; ++kt) {                                        \
            haA[kt] = *(const short8*)(&hbuf[0][rb][c][32 * kt + 8 * quad]);    \
            haB[kt] = *(const short8*)(&hbuf[1][rb][c][32 * kt + 8 * quad]);    \
        }                                                                       \
    }                                                                           \
    const int tn = (t + 1 < TT) ? t + 1 : TT - 1;                               \
    f32x4 na0 = z4, nb0 = z4, na1 = z4, nb1 = z4;                               \
    f32x4 ma0 = z4, mb0 = z4, ma1 = z4, mb1 = z4;                               \
    if (c < 2) {                                                                \
        if (USE_WS) {                                                           \
            XAN[0] = xwpA[(size_t)tn * 32];                                     \
            XAN[1] = xwpA[(size_t)tn * 32 + 16];                                \
            XBN[0] = xwpB[(size_t)tn * 32];                                     \
            XBN[1] = xwpB[(size_t)tn * 32 + 16];                                \
        } else {                                                                \
            const float* pA = xrowA + (size_t)tn * TD;                          \
            const float* pB = xrowB + (size_t)tn * TD;                          \
            na0 = *(const f32x4*)(pA);      nb0 = *(const f32x4*)(pA + 4);      \
            na1 = *(const f32x4*)(pA + 32); nb1 = *(const f32x4*)(pA + 36);     \
            ma0 = *(const f32x4*)(pB);      mb0 = *(const f32x4*)(pB + 4);      \
            ma1 = *(const f32x4*)(pB + 32); mb1 = *(const f32x4*)(pB + 36);     \
        }                                                                       \
    }                                                                           \
    /* x-MFMAs first: operands pre-ready, run during the ha ds_reads */         \
    f32x4 arA = z4, azA = z4, anhA = z4, anxA = z4;                             \
    f32x4 arB = z4, azB = z4, anhB = z4, anxB = z4;                             \
    _Pragma("unroll")                                                           \
    for (int kt = 0; kt < 2; ++kt) {                                            \
        arA  = __builtin_amdgcn_mfma_f32_16x16x32_bf16(XA[kt], wih[0][kt], arA , 0,0,0); \
        arB  = __builtin_amdgcn_mfma_f32_16x16x32_bf16(XB[kt], wih[0][kt], arB , 0,0,0); \
        azA  = __builtin_amdgcn_mfma_f32_16x16x32_bf16(XA[kt], wih[1][kt], azA , 0,0,0); \
        azB  = __builtin_amdgcn_mfma_f32_16x16x32_bf16(XB[kt], wih[1][kt], azB , 0,0,0); \
        anxA = __builtin_amdgcn_mfma_f32_16x16x32_bf16(XA[kt], wih[2][kt], anxA, 0,0,0); \
        anxB = __builtin_amdgcn_mfma_f32_16x16x32_bf16(XB[kt], wih[2][kt], anxB, 0,0,0); \
    }                                                                           \
    _Pragma("unroll")                                                           \
    for (int kt = 0; kt < 4; ++kt) {                                            \
        arA  = __builtin_amdgcn_mfma_f32_16x16x32_bf16(haA[kt], whh[0][kt], arA , 0,0,0); \
        arB  = __builtin_amdgcn_mfma_f32_16x16x32_bf16(haB[kt], whh[0][kt], arB , 0,0,0); \
        azA  = __builtin_amdgcn_mfma_f32_16x16x32_bf16(haA[kt], whh[1][kt], azA , 0,0,0); \
        azB  = __builtin_amdgcn_mfma_f32_16x16x32_bf16(haB[kt], whh[1][kt], azB , 0,0,0); \
        anhA = __builtin_amdgcn_mfma_f32_16x16x32_bf16(haA[kt], whh[2][kt], anhA, 0,0,0); \
        anhB = __builtin_amdgcn_mfma_f32_16x16x32_bf16(haB[kt], whh[2][kt], anhB, 0,0,0); \
    }                                                                           \
    /* logits for t-1: two waves on different SIMDs, one tile each */           \
    if (t > 0) {                                                                \
        const int lw = (t - 1) & 7;                                             \
        if (w == lw) {                                                          \
            f32x4 lacc = z4;                                                    \
            _Pragma("unroll")                                                   \
            for (int kt = 0; kt < 4; ++kt)                                      \
                lacc = __builtin_amdgcn_mfma_f32_16x16x32_bf16(haA[kt], wof[kt], lacc, 0,0,0); \
            if (c < 2 && quad == 0) {                                           \
                out[((size_t)(Bb + 0) * TT + (t - 1)) * 2 + c] = lacc[0] + boc; \
                out[((size_t)(Bb + 1) * TT + (t - 1)) * 2 + c] = lacc[1] + boc; \
            }                                                                   \
        }                                                                       \
        if (w == (lw ^ 4)) {                                                    \
            f32x4 lacc = z4;                                                    \
            _Pragma("unroll")                                                   \
            for (int kt = 0; kt < 4; ++kt)                                      \
                lacc = __builtin_amdgcn_mfma_f32_16x16x32_bf16(haB[kt], wof[kt], lacc, 0,0,0); \
            if (c < 2 && quad == 0) {                                           \
                out[((size_t)(Bb + 2) * TT + (t - 1)) * 2 + c] = lacc[0] + boc; \
                out[((size_t)(Bb + 3) * TT + (t - 1)) * 2 + c] = lacc[1] + boc; \
            }                                                                   \
        }                                                                       \
    }                                                                           \
    /* intra-wave exchange (same-wave DS ops are pipe-ordered: no barrier) */   \
    if (quad == 0) {                                                            \
        *(f32x4*)(&exws[w][0][0][c][0]) = arA;                                  \
        *(f32x4*)(&exws[w][0][1][c][0]) = azA;                                  \
        *(f32x4*)(&exws[w][0][2][c][0]) = anhA;                                 \
        *(f32x4*)(&exws[w][0][3][c][0]) = anxA;                                 \
        *(f32x4*)(&exws[w][1][0][c][0]) = arB;                                  \
        *(f32x4*)(&exws[w][1][1][c][0]) = azB;                                  \
        *(f32x4*)(&exws[w][1][2][c][0]) = anhB;                                 \
        *(f32x4*)(&exws[w][1][3][c][0]) = anxB;                                 \
    }                                                                           \
    WAVE_FENCE();                                                               \
    {                                                                           \
        float arS  = exws[w][tl][0][c][rw];                                     \
        float azS  = exws[w][tl][1][c][rw];                                     \
        float anhS = exws[w][tl][2][c][rw];                                     \
        float anxS = exws[w][tl][3][c][rw];                                     \
        float m    = mlds[t][quad];                                             \
        float er = __builtin_amdgcn_exp2f(__builtin_fmaf(arS, -LOG2E, crK));    \
        float r  = __builtin_amdgcn_rcpf(1.0f + er);                            \
        float ez = __builtin_amdgcn_exp2f(__builtin_fmaf(azS, -LOG2E, czK));    \
        float z  = __builtin_amdgcn_rcpf(1.0f + ez);                            \
        float p  = (anxS + bin) + r * (anhS + bhn);                             \
        float e2 = __builtin_amdgcn_exp2f(p * (2.0f * LOG2E));                  \
        float n  = __builtin_fmaf(-2.0f, __builtin_amdgcn_rcpf(1.0f + e2), 1.0f); \
        float hn = n + z * (hold - n);                                          \
        hold = hold + m * (hn - hold);                                          \
        hbuf[tl][wb][rw][jj] = bfb(hold);                                       \
    }                                                                           \
    if (!USE_WS && c < 2) {                                                     \
        short8 f0 = z8, f1 = z8, g0 = z8, g1 = z8;                              \
        _Pragma("unroll")                                                       \
        for (int j = 0; j < 4; ++j) {                                           \
            f0[j] = bfb(na0[j]); f0[4+j] = bfb(nb0[j]);                         \
            f1[j] = bfb(na1[j]); f1[4+j] = bfb(nb1[j]);                         \
            g0[j] = bfb(ma0[j]); g0[4+j] = bfb(mb0[j]);                         \
            g1[j] = bfb(ma1[j]); g1[4+j] = bfb(mb1[j]);                         \
        }                                                                       \
        XAN[0] = f0; XAN[1] = f1; XBN[0] = g0; XBN[1] = g1;                     \
    }                                                                           \
  }

    for (int t2 = 0; t2 < TT; t2 += 2) {
        STEP(t2,     xfA0, xfA1, xfB0, xfB1);
        STEP(t2 + 1, xfA1, xfA0, xfB1, xfB0);
    }
#undef STEP

    // flush logits for t = TT-1 (h(TT-1) sits in buffer 0)
    BAR();
    if (w == 0 || w == 4) {
        const int tile = (w == 0) ? 0 : 1;
        short8 ha[4];
        #pragma unroll
        for (int kt = 0; kt < 4; ++kt) ha[kt] = z8;
        if (c < 2) {
            #pragma unroll
            for (int kt = 0; kt < 4; ++kt)
                ha[kt] = *(const short8*)(&hbuf[tile][0][c][32 * kt + 8 * quad]);
        }
        f32x4 lacc = z4;
        #pragma unroll
        for (int kt = 0; kt < 4; ++kt)
            lacc = __builtin_amdgcn_mfma_f32_16x16x32_bf16(ha[kt], wof[kt], lacc, 0, 0, 0);
        if (c < 2 && quad == 0) {
            out[((size_t)(Bb + 2 * tile + 0) * TT + (TT - 1)) * 2 + c] = lacc[0] + boc;
            out[((size_t)(Bb + 2 * tile + 1) * TT + (TT - 1)) * 2 + c] = lacc[1] + boc;
        }
    }
}

extern "C" void kernel_launch(void* const* d_in, const int* in_sizes, int n_in,
                              void* d_out, int out_size, void* d_ws, size_t ws_size,
                              hipStream_t stream) {
    const float* x    = (const float*)d_in[0];
    const float* mask = (const float*)d_in[1];
    const float* w_ih = (const float*)d_in[2];
    const float* w_hh = (const float*)d_in[3];
    const float* b_ih = (const float*)d_in[4];
    const float* b_hh = (const float*)d_in[5];
    const float* Wo   = (const float*)d_in[6];
    const float* bo   = (const float*)d_in[7];
    float* out = (float*)d_out;
    (void)in_sizes; (void)n_in; (void)out_size;

    const size_t nfrag = (size_t)(TB / NRB) * TT * 2 * 16;      // 4.19M short8
    const size_t need  = nfrag * sizeof(short8);                // 67.1 MB
    if (ws_size >= need) {
        short8* xw = (short8*)d_ws;
        xswz<<<(int)(nfrag / 256), 256, 0, stream>>>(x, xw);
        gru_mfma<true><<<TB / NRB, 512, 0, stream>>>(x, xw, mask, w_ih, w_hh,
                                                     b_ih, b_hh, Wo, bo, out);
    } else {
        gru_mfma<false><<<TB / NRB, 512, 0, stream>>>(x, (const short8*)nullptr, mask,
                                                      w_ih, w_hh, b_ih, b_hh, Wo, bo, out);
    }
}